// Round 9
// baseline (53.511 us; speedup 1.0000x reference)
//
#include <hip/hip_runtime.h>
#include <math.h>

constexpr int N_ = 8, C_ = 256, H_ = 128, W_ = 128, G_ = 32;
constexpr int HW  = H_ * W_;        // 16384
constexpr int CHW = C_ * HW;        // 4194304

typedef float f4 __attribute__((ext_vector_type(4)));

// Soft barrier: LDS-drain + s_barrier, but NO vmcnt(0) drain -- prefetched
// global loads stay in flight across it (unlike __syncthreads, which hipcc
// lowers to s_waitcnt vmcnt(0) lgkmcnt(0) + s_barrier).
__device__ __forceinline__ void softbar() {
    asm volatile("s_waitcnt lgkmcnt(0)\n\ts_barrier" ::: "memory");
}

__device__ __forceinline__ f4 wave_reduce(const f4* v) {
    f4 s = v[0];
    #pragma unroll
    for (int k = 1; k < 8; ++k) s += v[k];
    s.x += __shfl_xor(s.x, 16); s.y += __shfl_xor(s.y, 16);
    s.z += __shfl_xor(s.z, 16); s.w += __shfl_xor(s.w, 16);
    s.x += __shfl_xor(s.x, 32); s.y += __shfl_xor(s.y, 32);
    s.z += __shfl_xor(s.z, 32); s.w += __shfl_xor(s.w, 32);
    return s;
}

__device__ __forceinline__ f4 block_sum(const f4 (*buf)[16], int q) {
    f4 sum = buf[0][q];
    #pragma unroll
    for (int w = 1; w < 8; ++w) sum += buf[w][q];
    return sum;
}

__device__ __forceinline__ f4 make_e(int m, f4 sum, float scale) {
    f4 e;
    e.x = (m & 1) ? sum.x * scale : 0.f;
    e.y = (m & 2) ? sum.y * scale : 0.f;
    e.z = (m & 4) ? sum.z * scale : 0.f;
    e.w = (m & 8) ? sum.w * scale : 0.f;
    return e;
}

__device__ __forceinline__ void load_tile(f4* v, const float* xp) {
    #pragma unroll
    for (int k = 0; k < 8; ++k)
        v[k] = *reinterpret_cast<const f4*>(xp + (size_t)(32 * k) * HW);
}

__device__ __forceinline__ void store_tile(float* op, const f4* v, f4 e) {
    #pragma unroll
    for (int k = 0; k < 8; ++k) {
        f4 o = v[k] + e;
        __builtin_nontemporal_store(o, reinterpret_cast<f4*>(op + (size_t)(32 * k) * HW));
    }
}

// 4-subtile software-pipelined fused kernel.
// Block = 2 rows (256 px) x 256 ch = subtiles S0..S3 of (64 px x 256 ch).
// Per subtile & thread: 8 f4 in registers (c0 = tid>>4 channel group,
// q = tid&15 pixel f4 -> 16 lanes x 256 B contiguous per instruction).
// Schedule: load S0,S1 -> masks -> [reduce St | prefetch St+2 | softbar |
// finish+store St] -- loads of t+2 in flight across the barrier and during
// the store of t, so machine-wide read & write streams overlap.
__global__ __launch_bounds__(512) void fused_exc_kernel(
    const float* __restrict__ x, const float* __restrict__ bb,
    const int* __restrict__ stride_p, const int* __restrict__ epoch_p,
    float* __restrict__ out)
{
    __shared__ f4 psum[2][8][16];     // double-buffered wave partials

    int bid  = blockIdx.x;            // 512 blocks: (n, row-pair)
    int n    = bid >> 6;
    int rp   = bid & 63;
    int row0 = rp << 1;

    int tid  = threadIdx.x;
    int wv   = tid >> 6;              // wave 0..7
    int lane = tid & 63;
    int c0   = tid >> 4;              // channel group 0..31 (8 ch each)
    int q    = tid & 15;              // f4 index within a 64-px subtile

    size_t base = (size_t)n * CHW + (size_t)c0 * HW + (size_t)row0 * W_ + q * 4;
    size_t g0 = base, g1 = base + 64, g2 = base + W_, g3 = base + W_ + 64;

    f4 v0[8], v1[8], v2[8], v3[8];
    load_tile(v0, x + g0);
    load_tile(v1, x + g1);

    // --- masks + schedule scalars, in the shadow of the S0/S1 loads ---
    float inv   = 1.0f / (float)(*stride_p);
    float alpha = 0.5f * (1.0f + cosf((float)M_PI * (float)(*epoch_p) / 22.0f));
    float scale = alpha / (float)C_;

    float hf0 = (float)row0, hf1 = (float)(row0 + 1);
    float wA  = (float)(q * 4), wB = wA + 64.0f;
    const f4* bbp = reinterpret_cast<const f4*>(bb) + n * G_;   // wave-uniform
    int m0 = 0, m1 = 0, m2 = 0, m3 = 0;
    #pragma unroll 4
    for (int g = 0; g < G_; ++g) {
        f4 bv = bbp[g];
        float bx1 = floorf(bv.x * inv), by1 = floorf(bv.y * inv);
        float bx2 = ceilf (bv.z * inv), by2 = ceilf (bv.w * inv);
        int wa = 0, wb = 0;
        #pragma unroll
        for (int j = 0; j < 4; ++j) {
            float fA = wA + (float)j, fB = wB + (float)j;
            if (fA >= bx1 && fA < bx2) wa |= 1 << j;
            if (fB >= bx1 && fB < bx2) wb |= 1 << j;
        }
        if (hf0 >= by1 && hf0 < by2) { m0 |= wa; m1 |= wb; }
        if (hf1 >= by1 && hf1 < by2) { m2 |= wa; m3 |= wb; }
    }

    // --- S0: reduce, prefetch S2, barrier, finish+store ---
    { f4 s = wave_reduce(v0); if (lane < 16) psum[0][wv][q] = s; }
    load_tile(v2, x + g2);            // in flight across the soft barrier
    softbar();
    store_tile(out + g0, v0, make_e(m0, block_sum(psum[0], q), scale));

    // --- S1: reduce, prefetch S3, barrier, finish+store ---
    { f4 s = wave_reduce(v1); if (lane < 16) psum[1][wv][q] = s; }
    load_tile(v3, x + g3);
    softbar();
    store_tile(out + g1, v1, make_e(m1, block_sum(psum[1], q), scale));

    // --- S2 ---
    { f4 s = wave_reduce(v2); if (lane < 16) psum[0][wv][q] = s; }
    softbar();
    store_tile(out + g2, v2, make_e(m2, block_sum(psum[0], q), scale));

    // --- S3 ---
    { f4 s = wave_reduce(v3); if (lane < 16) psum[1][wv][q] = s; }
    softbar();
    store_tile(out + g3, v3, make_e(m3, block_sum(psum[1], q), scale));
}

extern "C" void kernel_launch(void* const* d_in, const int* in_sizes, int n_in,
                              void* d_out, int out_size, void* d_ws, size_t ws_size,
                              hipStream_t stream) {
    const float* x  = (const float*)d_in[0];
    const float* bb = (const float*)d_in[1];
    const int* stride_p = (const int*)d_in[2];
    const int* epoch_p  = (const int*)d_in[3];
    float* out = (float*)d_out;

    int grid = N_ * H_ / 2;   // 512 blocks, one per row-pair
    fused_exc_kernel<<<grid, 512, 0, stream>>>(x, bb, stride_p, epoch_p, out);
}

// Round 10
// 48.590 us; speedup vs baseline: 1.1013x; 1.1013x over previous
//
#include <hip/hip_runtime.h>
#include <math.h>

constexpr int N_ = 8, C_ = 256, H_ = 128, W_ = 128, G_ = 32;
constexpr int HW  = H_ * W_;        // 16384
constexpr int CHW = C_ * HW;        // 4194304

typedef float f4 __attribute__((ext_vector_type(4)));

// Inline-asm load: the result is an opaque asm output, so the compiler
// CANNOT rematerialize/re-load it -- it must stay register-resident until
// consumed. (Every HIP-load version of this kernel got demoted to a
// load-twice form: VGPR_Count 44/48/72 vs the >=64 a resident tile needs.)
__device__ __forceinline__ f4 forced_load(const float* p) {
    f4 r;
    asm volatile("global_load_dwordx4 %0, %1, off" : "=v"(r) : "v"(p));
    return r;
}

__global__ __launch_bounds__(512) void fused_exc_kernel(
    const float* __restrict__ x, const float* __restrict__ bb,
    const int* __restrict__ stride_p, const int* __restrict__ epoch_p,
    float* __restrict__ out)
{
    __shared__ f4 psum[2][8][16];     // wave partials (A,B)

    int bid = blockIdx.x;             // 1024 blocks, one per (n,row)
    int n   = bid >> 7;               // 8 n
    int row = bid & 127;              // 128 rows

    int tid  = threadIdx.x;
    int wv   = tid >> 6;              // wave 0..7
    int lane = tid & 63;
    int c0   = tid >> 4;              // channel group 0..31 (8 ch each)
    int q    = tid & 15;              // f4 index within a 64-px half-row

    size_t gA = (size_t)n * CHW + (size_t)c0 * HW + (size_t)row * W_ + q * 4;
    size_t gB = gA + 64;              // second half of the row
    const float* xpA = x + gA;
    const float* xpB = x + gB;

    // Issue ALL 16 loads (forced-resident, max outstanding).
    f4 vA[8], vB[8];
    #pragma unroll
    for (int k = 0; k < 8; ++k) vA[k] = forced_load(xpA + (size_t)(32 * k) * HW);
    #pragma unroll
    for (int k = 0; k < 8; ++k) vB[k] = forced_load(xpB + (size_t)(32 * k) * HW);

    // --- independent of x: schedule scalars + masks (in the load shadow) ---
    float inv   = 1.0f / (float)(*stride_p);
    float alpha = 0.5f * (1.0f + cosf((float)M_PI * (float)(*epoch_p) / 22.0f));
    float scale = alpha / (float)C_;

    float hf  = (float)row;
    float w0A = (float)(q * 4);
    float w0B = w0A + 64.0f;
    const f4* bbp = reinterpret_cast<const f4*>(bb) + n * G_;   // wave-uniform
    int mA = 0, mB = 0;
    #pragma unroll 4
    for (int g = 0; g < G_; ++g) {
        f4 bv = bbp[g];
        float x1 = floorf(bv.x * inv), y1 = floorf(bv.y * inv);
        float x2 = ceilf (bv.z * inv), y2 = ceilf (bv.w * inv);
        if (hf >= y1 && hf < y2) {
            #pragma unroll
            for (int j = 0; j < 4; ++j) {
                float wfA = w0A + (float)j;
                float wfB = w0B + (float)j;
                if (wfA >= x1 && wfA < x2) mA |= 1 << j;
                if (wfB >= x1 && wfB < x2) mB |= 1 << j;
            }
        }
    }

    // Drain the asm loads; fence instruction motion across the wait (rule #18).
    asm volatile("s_waitcnt vmcnt(0)" ::: "memory");
    __builtin_amdgcn_sched_barrier(0);

    // --- reduce A ---
    f4 sA = vA[0];
    #pragma unroll
    for (int k = 1; k < 8; ++k) sA += vA[k];
    sA.x += __shfl_xor(sA.x, 16); sA.y += __shfl_xor(sA.y, 16);
    sA.z += __shfl_xor(sA.z, 16); sA.w += __shfl_xor(sA.w, 16);
    sA.x += __shfl_xor(sA.x, 32); sA.y += __shfl_xor(sA.y, 32);
    sA.z += __shfl_xor(sA.z, 32); sA.w += __shfl_xor(sA.w, 32);
    if (lane < 16) psum[0][wv][q] = sA;

    // --- reduce B ---
    f4 sB = vB[0];
    #pragma unroll
    for (int k = 1; k < 8; ++k) sB += vB[k];
    sB.x += __shfl_xor(sB.x, 16); sB.y += __shfl_xor(sB.y, 16);
    sB.z += __shfl_xor(sB.z, 16); sB.w += __shfl_xor(sB.w, 16);
    sB.x += __shfl_xor(sB.x, 32); sB.y += __shfl_xor(sB.y, 32);
    sB.z += __shfl_xor(sB.z, 32); sB.w += __shfl_xor(sB.w, 32);
    if (lane < 16) psum[1][wv][q] = sB;

    __syncthreads();   // vmcnt already 0 -> this drain is free

    // --- finish + store A (vA guaranteed in registers) ---
    f4 sumA = psum[0][0][q];
    #pragma unroll
    for (int w = 1; w < 8; ++w) sumA += psum[0][w][q];
    f4 eA;
    eA.x = (mA & 1) ? sumA.x * scale : 0.f;
    eA.y = (mA & 2) ? sumA.y * scale : 0.f;
    eA.z = (mA & 4) ? sumA.z * scale : 0.f;
    eA.w = (mA & 8) ? sumA.w * scale : 0.f;
    float* opA = out + gA;
    #pragma unroll
    for (int k = 0; k < 8; ++k) {
        f4 o = vA[k] + eA;
        __builtin_nontemporal_store(o, reinterpret_cast<f4*>(opA + (size_t)(32 * k) * HW));
    }

    // --- finish + store B ---
    f4 sumB = psum[1][0][q];
    #pragma unroll
    for (int w = 1; w < 8; ++w) sumB += psum[1][w][q];
    f4 eB;
    eB.x = (mB & 1) ? sumB.x * scale : 0.f;
    eB.y = (mB & 2) ? sumB.y * scale : 0.f;
    eB.z = (mB & 4) ? sumB.z * scale : 0.f;
    eB.w = (mB & 8) ? sumB.w * scale : 0.f;
    float* opB = out + gB;
    #pragma unroll
    for (int k = 0; k < 8; ++k) {
        f4 o = vB[k] + eB;
        __builtin_nontemporal_store(o, reinterpret_cast<f4*>(opB + (size_t)(32 * k) * HW));
    }
}

extern "C" void kernel_launch(void* const* d_in, const int* in_sizes, int n_in,
                              void* d_out, int out_size, void* d_ws, size_t ws_size,
                              hipStream_t stream) {
    const float* x  = (const float*)d_in[0];
    const float* bb = (const float*)d_in[1];
    const int* stride_p = (const int*)d_in[2];
    const int* epoch_p  = (const int*)d_in[3];
    float* out = (float*)d_out;

    int grid = N_ * H_;   // 1024 blocks, one per row
    fused_exc_kernel<<<grid, 512, 0, stream>>>(x, bb, stride_p, epoch_p, out);
}

// Round 11
// 47.135 us; speedup vs baseline: 1.1353x; 1.0309x over previous
//
#include <hip/hip_runtime.h>
#include <math.h>

constexpr int N_ = 8, C_ = 256, H_ = 128, W_ = 128, G_ = 32;
constexpr int HW  = H_ * W_;        // 16384
constexpr int CHW = C_ * HW;        // 4194304

typedef float f4 __attribute__((ext_vector_type(4)));

// Forced-resident load (R10-proven): asm output cannot be rematerialized.
__device__ __forceinline__ f4 forced_load(const float* p) {
    f4 r;
    asm volatile("global_load_dwordx4 %0, %1, off" : "=v"(r) : "v"(p));
    return r;
}

// 256-thread block = one 64-px x 256-ch tile, 16 f4/thread (16 channels).
// c0 = tid>>4 (16 channel groups), q = tid&15 (pixel f4; 16 lanes x 16B =
// 256 B contiguous per instruction -- same as the 47 us variants).
// 4-wave barrier instead of 8-wave; 2048 blocks oversubscribe the machine
// (~4 resident/CU + rolling dispatch) so read/write phases of different
// blocks stagger instead of running lockstep.
__global__ __launch_bounds__(256) void fused_exc_kernel(
    const float* __restrict__ x, const float* __restrict__ bb,
    const int* __restrict__ stride_p, const int* __restrict__ epoch_p,
    float* __restrict__ out)
{
    __shared__ f4 psum[4][16];        // 4 wave partials

    int bid  = blockIdx.x;            // 2048 blocks: (n, row, half)
    int n    = bid >> 8;
    int rem  = bid & 255;
    int row  = rem >> 1;
    int half = rem & 1;

    int tid  = threadIdx.x;
    int wv   = tid >> 6;              // wave 0..3
    int lane = tid & 63;
    int c0   = tid >> 4;              // channel group 0..15 (16 ch each)
    int q    = tid & 15;              // f4 index within the 64-px tile

    // thread covers channels c = c0 + 16*k, k = 0..15
    size_t goff = (size_t)n * CHW + (size_t)c0 * HW
                + (size_t)row * W_ + half * 64 + q * 4;
    const float* xp = x + goff;

    f4 v[16];
    #pragma unroll
    for (int k = 0; k < 16; ++k)
        v[k] = forced_load(xp + (size_t)(16 * k) * HW);

    // --- independent of x: schedule scalars + mask (in the load shadow) ---
    float inv   = 1.0f / (float)(*stride_p);
    float alpha = 0.5f * (1.0f + cosf((float)M_PI * (float)(*epoch_p) / 22.0f));
    float scale = alpha / (float)C_;

    float hf = (float)row;
    float w0 = (float)(half * 64 + q * 4);
    const f4* bbp = reinterpret_cast<const f4*>(bb) + n * G_;   // wave-uniform
    int m = 0;
    #pragma unroll 4
    for (int g = 0; g < G_; ++g) {
        f4 bv = bbp[g];
        float x1 = floorf(bv.x * inv), y1 = floorf(bv.y * inv);
        float x2 = ceilf (bv.z * inv), y2 = ceilf (bv.w * inv);
        if (hf >= y1 && hf < y2) {
            #pragma unroll
            for (int j = 0; j < 4; ++j) {
                float wf = w0 + (float)j;
                if (wf >= x1 && wf < x2) m |= 1 << j;
            }
        }
    }

    // Drain the asm loads; fence motion across the wait (rule #18).
    asm volatile("s_waitcnt vmcnt(0)" ::: "memory");
    __builtin_amdgcn_sched_barrier(0);

    // --- reduce: 16 channels locally, then fold the wave's 4 c0-groups ---
    f4 s = v[0];
    #pragma unroll
    for (int k = 1; k < 16; ++k) s += v[k];
    s.x += __shfl_xor(s.x, 16); s.y += __shfl_xor(s.y, 16);
    s.z += __shfl_xor(s.z, 16); s.w += __shfl_xor(s.w, 16);
    s.x += __shfl_xor(s.x, 32); s.y += __shfl_xor(s.y, 32);
    s.z += __shfl_xor(s.z, 32); s.w += __shfl_xor(s.w, 32);
    if (lane < 16) psum[wv][q] = s;   // 64-channel partial per wave

    __syncthreads();   // vmcnt already 0 -> drain-free

    f4 sum = psum[0][q];
    #pragma unroll
    for (int w = 1; w < 4; ++w) sum += psum[w][q];

    f4 e4;
    e4.x = (m & 1) ? sum.x * scale : 0.f;
    e4.y = (m & 2) ? sum.y * scale : 0.f;
    e4.z = (m & 4) ? sum.z * scale : 0.f;
    e4.w = (m & 8) ? sum.w * scale : 0.f;

    float* op = out + goff;
    #pragma unroll
    for (int k = 0; k < 16; ++k) {
        f4 o = v[k] + e4;
        __builtin_nontemporal_store(o, reinterpret_cast<f4*>(op + (size_t)(16 * k) * HW));
    }
}

extern "C" void kernel_launch(void* const* d_in, const int* in_sizes, int n_in,
                              void* d_out, int out_size, void* d_ws, size_t ws_size,
                              hipStream_t stream) {
    const float* x  = (const float*)d_in[0];
    const float* bb = (const float*)d_in[1];
    const int* stride_p = (const int*)d_in[2];
    const int* epoch_p  = (const int*)d_in[3];
    float* out = (float*)d_out;

    int grid = N_ * H_ * 2;   // 2048 blocks, one per 64-px tile
    fused_exc_kernel<<<grid, 256, 0, stream>>>(x, bb, stride_p, epoch_p, out);
}